// Round 1
// baseline (11627.979 us; speedup 1.0000x reference)
//
#include <hip/hip_runtime.h>
#include <hip/hip_bf16.h>
#include <stdint.h>

// SeqLSTM: 2-layer LSTM (B=256,T=512,IN=64,H=512) + MLP head.
// Persistent gate-partitioned kernel: 256 WGs = 4 batch groups x 64 gate chunks.
// Weights LDS-resident (bf16, XOR-swizzled); h exchanged via global bf16 rings;
// cross-WG sync via agent-scope flag counters. Layers pipelined with 1-step skew.

#define Bsz 256
#define Tsz 512
#define IND 64
#define Hsz 512
#define NGROW 32      // gate rows per chunk (4 gates x 8 h-elems)
#define HC 8          // h elems per chunk
#define W0S 640       // LDS row stride (64+512 padded to allow XOR swizzle)
#define W1S 1024
#define FLAG_STRIDE 16  // ints -> 64B per flag line

typedef __attribute__((ext_vector_type(8))) short short8;
typedef __attribute__((ext_vector_type(4))) float floatx4;

static __device__ __forceinline__ short f2bf(float f) {
    unsigned u = __float_as_uint(f);
    u += 0x7FFFu + ((u >> 16) & 1u);   // RNE
    return (short)(u >> 16);
}
static __device__ __forceinline__ float bf2f(short s) {
    return __uint_as_float(((unsigned)(unsigned short)s) << 16);
}
static __device__ __forceinline__ float sigm(float z) { return 1.f / (1.f + __expf(-z)); }
static __device__ __forceinline__ float tanh_f(float z) { return 2.f / (1.f + __expf(-2.f * z)) - 1.f; }

// acc[m][0] cols: i(e=0..7),f(e=0..7); acc[m][1] cols: g,o.  C layout: col=lane&15,row=(lane>>4)*4+r.
static __device__ __forceinline__ void act_store(
    floatx4 (&acc)[2][2], floatx4& c0, floatx4& c1,
    float bI, float bF, float bG, float bO,
    bool lo, int q, int e, int rowbase, int hcol, short* __restrict__ hout)
{
#pragma unroll
    for (int m = 0; m < 2; ++m) {
        floatx4 gi = acc[m][0];
        floatx4 gg = acc[m][1];
        float si[4], sg[4];
#pragma unroll
        for (int r = 0; r < 4; ++r) {
            si[r] = __shfl_xor(gi[r], 8);
            sg[r] = __shfl_xor(gg[r], 8);
        }
        floatx4& c = m ? c1 : c0;
#pragma unroll
        for (int r = 0; r < 4; ++r) {
            float iz = (lo ? gi[r] : si[r]) + bI;
            float fz = (lo ? si[r] : gi[r]) + bF;
            float gz = (lo ? gg[r] : sg[r]) + bG;
            float oz = (lo ? sg[r] : gg[r]) + bO;
            float ii = sigm(iz);
            float ff = sigm(fz);
            float gv = tanh_f(gz);
            float oo = sigm(oz);
            float cn = ff * c[r] + ii * gv;
            c[r] = cn;
            float hv = oo * tanh_f(cn);
            if (lo) {
                hout[(size_t)(rowbase + m * 16 + q * 4 + r) * Hsz + hcol + e] = f2bf(hv);
            }
        }
    }
}

__global__ __launch_bounds__(256, 1) void lstm_pers(
    const float* __restrict__ x,
    const float* __restrict__ Wih0, const float* __restrict__ Whh0,
    const float* __restrict__ bih0, const float* __restrict__ bhh0,
    const float* __restrict__ Wih1, const float* __restrict__ Whh1,
    const float* __restrict__ bih1, const float* __restrict__ bhh1,
    int* __restrict__ flags, short* __restrict__ h1ring, short* __restrict__ h2ring)
{
    __shared__ __align__(16) short w0[NGROW * W0S];   // [32][640] layer0: [Wih0 | Whh0]
    __shared__ __align__(16) short w1[NGROW * W1S];   // [32][1024] layer1: [Wih1 | Whh1]

    const int tid = threadIdx.x;
    const int bid = blockIdx.x;
    const int grp = bid >> 6;     // batch group 0..3 (64 rows each)
    const int chunk = bid & 63;   // h-chunk 0..63 (8 h elems)

    // ---- one-time: stage weight slices to LDS (bf16, XOR-swizzled within row) ----
    for (int idx = tid; idx < NGROW * 576; idx += 256) {
        int n = idx / 576;
        int k = idx - n * 576;
        int grow = (n >> 3) * Hsz + chunk * HC + (n & 7);
        float v = (k < IND) ? Wih0[grow * IND + k] : Whh0[grow * Hsz + (k - IND)];
        w0[n * W0S + (k ^ ((n & 7) << 4))] = f2bf(v);
    }
    for (int idx = tid; idx < NGROW * 1024; idx += 256) {
        int n = idx >> 10;
        int k = idx & 1023;
        int grow = (n >> 3) * Hsz + chunk * HC + (n & 7);
        float v = (k < Hsz) ? Wih1[grow * Hsz + k] : Whh1[grow * Hsz + (k - Hsz)];
        w1[n * W1S + (k ^ ((n & 7) << 4))] = f2bf(v);
    }

    const int lane = tid & 63;
    const int wv = tid >> 6;
    const int layer = wv >> 1;          // waves 0,1 -> layer0 ; waves 2,3 -> layer1
    const int wrow = (wv & 1) * 32;     // M-half
    const int q = lane >> 4;
    const int cl = lane & 15;
    const int e = lane & 7;
    const bool lo = cl < 8;
    const int rowbase = grp * 64 + wrow;
    const int hcol = chunk * HC;

    float bI, bF, bG, bO;
    {
        const float* bi = layer ? bih1 : bih0;
        const float* bh = layer ? bhh1 : bhh0;
        int hix = chunk * HC + e;
        bI = bi[hix] + bh[hix];
        bF = bi[Hsz + hix] + bh[Hsz + hix];
        bG = bi[2 * Hsz + hix] + bh[2 * Hsz + hix];
        bO = bi[3 * Hsz + hix] + bh[3 * Hsz + hix];
    }

    __syncthreads();

    floatx4 c0 = {0.f, 0.f, 0.f, 0.f};
    floatx4 c1 = {0.f, 0.f, 0.f, 0.f};
    const int fbase = grp * 512;

    for (int k = 0; k <= Tsz; ++k) {
        // ---- wait for previous iteration (h1[k-1] complete, h2[k-2] complete) ----
        if (k > 0) {
            int* fp = &flags[(fbase + k - 1) * FLAG_STRIDE];
            int spins = 0;
            while (__hip_atomic_load(fp, __ATOMIC_RELAXED, __HIP_MEMORY_SCOPE_AGENT) < 64) {
                __builtin_amdgcn_s_sleep(4);
                if (++spins > (1 << 24)) break;   // deadlock safety valve
            }
            (void)__hip_atomic_load(fp, __ATOMIC_ACQUIRE, __HIP_MEMORY_SCOPE_AGENT);
        }

        if (layer == 0) {
            if (k < Tsz) {
                const int t = k;
                const short* h1p = h1ring + (size_t)((k + 1) & 1) * (Bsz * Hsz);  // h1[k-1] (zeros at k=0)
                floatx4 acc[2][2];
#pragma unroll
                for (int m = 0; m < 2; ++m) {
                    acc[m][0] = (floatx4){0.f, 0.f, 0.f, 0.f};
                    acc[m][1] = (floatx4){0.f, 0.f, 0.f, 0.f};
                }
#pragma unroll
                for (int ks = 0; ks < 18; ++ks) {
                    const int kk = ks * 32;
                    short8 a0, a1;
                    if (ks < 2) {
                        // x part (fp32 -> bf16)
#pragma unroll
                        for (int m = 0; m < 2; ++m) {
                            const float* xp = x + ((size_t)(rowbase + m * 16 + cl) * Tsz + t) * IND + kk + q * 8;
                            floatx4 v0 = *(const floatx4*)xp;
                            floatx4 v1 = *(const floatx4*)(xp + 4);
                            short8 av;
                            av[0] = f2bf(v0[0]); av[1] = f2bf(v0[1]); av[2] = f2bf(v0[2]); av[3] = f2bf(v0[3]);
                            av[4] = f2bf(v1[0]); av[5] = f2bf(v1[1]); av[6] = f2bf(v1[2]); av[7] = f2bf(v1[3]);
                            if (m == 0) a0 = av; else a1 = av;
                        }
                    } else {
                        a0 = *(const short8*)(h1p + (size_t)(rowbase + cl) * Hsz + (kk - 64) + q * 8);
                        a1 = *(const short8*)(h1p + (size_t)(rowbase + 16 + cl) * Hsz + (kk - 64) + q * 8);
                    }
#pragma unroll
                    for (int nt = 0; nt < 2; ++nt) {
                        const int n = nt * 16 + cl;
                        const int col = (kk + q * 8) ^ ((n & 7) << 4);
                        short8 bb = *(const short8*)(&w0[n * W0S + col]);
                        acc[0][nt] = __builtin_amdgcn_mfma_f32_16x16x32_bf16(a0, bb, acc[0][nt], 0, 0, 0);
                        acc[1][nt] = __builtin_amdgcn_mfma_f32_16x16x32_bf16(a1, bb, acc[1][nt], 0, 0, 0);
                    }
                }
                short* h1o = h1ring + (size_t)(k & 1) * (Bsz * Hsz);  // h1[k]
                act_store(acc, c0, c1, bI, bF, bG, bO, lo, q, e, rowbase, hcol, h1o);
            }
        } else {
            if (k >= 1) {
                const short* h1p = h1ring + (size_t)((k + 1) & 1) * (Bsz * Hsz);  // h1[k-1]
                const short* h2p = h2ring + (size_t)(k & 1) * (Bsz * Hsz);        // h2[k-2] (zeros at k=1)
                floatx4 acc[2][2];
#pragma unroll
                for (int m = 0; m < 2; ++m) {
                    acc[m][0] = (floatx4){0.f, 0.f, 0.f, 0.f};
                    acc[m][1] = (floatx4){0.f, 0.f, 0.f, 0.f};
                }
#pragma unroll
                for (int ks = 0; ks < 32; ++ks) {
                    const int kk = ks * 32;
                    const short* s0 = (kk < Hsz)
                        ? (h1p + (size_t)(rowbase + cl) * Hsz + kk + q * 8)
                        : (h2p + (size_t)(rowbase + cl) * Hsz + (kk - Hsz) + q * 8);
                    const short* s1 = (kk < Hsz)
                        ? (h1p + (size_t)(rowbase + 16 + cl) * Hsz + kk + q * 8)
                        : (h2p + (size_t)(rowbase + 16 + cl) * Hsz + (kk - Hsz) + q * 8);
                    short8 a0 = *(const short8*)s0;
                    short8 a1 = *(const short8*)s1;
#pragma unroll
                    for (int nt = 0; nt < 2; ++nt) {
                        const int n = nt * 16 + cl;
                        const int col = (kk + q * 8) ^ ((n & 7) << 4);
                        short8 bb = *(const short8*)(&w1[n * W1S + col]);
                        acc[0][nt] = __builtin_amdgcn_mfma_f32_16x16x32_bf16(a0, bb, acc[0][nt], 0, 0, 0);
                        acc[1][nt] = __builtin_amdgcn_mfma_f32_16x16x32_bf16(a1, bb, acc[1][nt], 0, 0, 0);
                    }
                }
                short* h2o = h2ring + (size_t)((k + 1) & 1) * (Bsz * Hsz);  // h2[k-1]
                act_store(acc, c0, c1, bI, bF, bG, bO, lo, q, e, rowbase, hcol, h2o);
            }
        }

        __syncthreads();   // all waves' stores drained (compiler emits vmcnt(0) before barrier)
        if (k < Tsz && tid == 0) {
            __hip_atomic_fetch_add(&flags[(fbase + k) * FLAG_STRIDE], 1,
                                   __ATOMIC_RELEASE, __HIP_MEMORY_SCOPE_AGENT);
        }
    }
}

// head: out = sigmoid(relu(h2_last @ W1^T + b1) @ W2^T + b2)
__global__ __launch_bounds__(256) void head_kernel(
    const short* __restrict__ h2,   // final h2 (slot 1), [256][512] bf16
    const float* __restrict__ W1, const float* __restrict__ b1,
    const float* __restrict__ W2, const float* __restrict__ b2,
    float* __restrict__ out)
{
    __shared__ float hid[4][256];
    const int tid = threadIdx.x;
    const int r0 = blockIdx.x * 4;
    float acc[4] = {0.f, 0.f, 0.f, 0.f};
    const float* wrow = W1 + (size_t)tid * 512;
    for (int kk = 0; kk < 512; kk += 8) {
        float w[8];
#pragma unroll
        for (int j = 0; j < 8; ++j) w[j] = wrow[kk + j];
#pragma unroll
        for (int r = 0; r < 4; ++r) {
            short8 hv = *(const short8*)(h2 + (size_t)(r0 + r) * 512 + kk);
#pragma unroll
            for (int j = 0; j < 8; ++j) acc[r] += w[j] * bf2f(hv[j]);
        }
    }
#pragma unroll
    for (int r = 0; r < 4; ++r) hid[r][tid] = fmaxf(acc[r] + b1[tid], 0.f);
    __syncthreads();
    const int wv = tid >> 6, lane = tid & 63;
    float s = 0.f;
    for (int j = lane; j < 256; j += 64) s += hid[wv][j] * W2[j];
#pragma unroll
    for (int off = 32; off; off >>= 1) s += __shfl_down(s, off, 64);
    if (lane == 0) out[r0 + wv] = 1.f / (1.f + __expf(-(s + b2[0])));
}

extern "C" void kernel_launch(void* const* d_in, const int* in_sizes, int n_in,
                              void* d_out, int out_size, void* d_ws, size_t ws_size,
                              hipStream_t stream) {
    const float* x    = (const float*)d_in[0];
    const float* Wih0 = (const float*)d_in[1];
    const float* Whh0 = (const float*)d_in[2];
    const float* bih0 = (const float*)d_in[3];
    const float* bhh0 = (const float*)d_in[4];
    const float* Wih1 = (const float*)d_in[5];
    const float* Whh1 = (const float*)d_in[6];
    const float* bih1 = (const float*)d_in[7];
    const float* bhh1 = (const float*)d_in[8];
    const float* W1   = (const float*)d_in[9];
    const float* b1   = (const float*)d_in[10];
    const float* W2   = (const float*)d_in[11];
    const float* b2   = (const float*)d_in[12];
    float* out = (float*)d_out;

    const size_t FLAGS_BYTES = (size_t)4 * 512 * FLAG_STRIDE * sizeof(int);  // 128 KB
    const size_t RING_BYTES  = (size_t)2 * Bsz * Hsz * sizeof(short);        // 512 KB
    if (ws_size < FLAGS_BYTES + 2 * RING_BYTES) return;

    char* ws = (char*)d_ws;
    int*   flags  = (int*)ws;
    short* h1ring = (short*)(ws + FLAGS_BYTES);
    short* h2ring = (short*)(ws + FLAGS_BYTES + RING_BYTES);

    // zero flags + rings (rings double as the h[-1]=0 initial state)
    hipMemsetAsync(d_ws, 0, FLAGS_BYTES + 2 * RING_BYTES, stream);

    void* args[] = {
        (void*)&x,
        (void*)&Wih0, (void*)&Whh0, (void*)&bih0, (void*)&bhh0,
        (void*)&Wih1, (void*)&Whh1, (void*)&bih1, (void*)&bhh1,
        (void*)&flags, (void*)&h1ring, (void*)&h2ring
    };
    hipLaunchCooperativeKernel((const void*)lstm_pers, dim3(256), dim3(256), args, 0, stream);

    const short* h2last = h2ring + (size_t)Bsz * Hsz;  // slot 1 holds h2[T-1]
    head_kernel<<<dim3(64), dim3(256), 0, stream>>>(h2last, W1, b1, W2, b2, out);
}

// Round 3
// 8675.715 us; speedup vs baseline: 1.3403x; 1.3403x over previous
//
#include <hip/hip_runtime.h>
#include <hip/hip_bf16.h>
#include <stdint.h>

// SeqLSTM: 2-layer LSTM (B=256,T=512,IN=64,H=512) + MLP head.
// Persistent gate-partitioned kernel: 256 WGs = 4 batch groups x 64 gate chunks.
// Weights LDS-resident (bf16, XOR-swizzled); h exchanged via global bf16 rings
// accessed with RELAXED agent-scope atomics (per-access sc1 coherence, no
// buffer_inv/wbl2 bulk cache ops); cross-WG sync via relaxed flag counters
// ordered by the pre-barrier vmcnt(0) drain. Layers pipelined with 1-step skew.

#define Bsz 256
#define Tsz 512
#define IND 64
#define Hsz 512
#define NGROW 32      // gate rows per chunk (4 gates x 8 h-elems)
#define HC 8          // h elems per chunk
#define W0S 640       // LDS row stride (64+512 padded to allow XOR swizzle)
#define W1S 1024
#define FLAG_STRIDE 16  // ints -> 64B per flag line

typedef __attribute__((ext_vector_type(8))) short short8;
typedef __attribute__((ext_vector_type(4))) float floatx4;
typedef unsigned long long u64;

static __device__ __forceinline__ short f2bf(float f) {
    unsigned u = __float_as_uint(f);
    u += 0x7FFFu + ((u >> 16) & 1u);   // RNE
    return (short)(u >> 16);
}
static __device__ __forceinline__ float bf2f(short s) {
    return __uint_as_float(((unsigned)(unsigned short)s) << 16);
}
static __device__ __forceinline__ float sigm(float z) { return 1.f / (1.f + __expf(-z)); }
static __device__ __forceinline__ float tanh_f(float z) { return 2.f / (1.f + __expf(-2.f * z)) - 1.f; }

// 16B device-coherent ring load: two relaxed agent-scope 8B atomic loads
// (lower to global_load_dwordx2 sc1 — pipelined, no cache maintenance).
static __device__ __forceinline__ short8 ring_ld(const short* p) {
    struct u64x2 { u64 a, b; } t;
    t.a = __hip_atomic_load((const u64*)p,     __ATOMIC_RELAXED, __HIP_MEMORY_SCOPE_AGENT);
    t.b = __hip_atomic_load((const u64*)p + 1, __ATOMIC_RELAXED, __HIP_MEMORY_SCOPE_AGENT);
    return __builtin_bit_cast(short8, t);
}

// acc[m][0] cols: i(e=0..7),f(e=0..7); acc[m][1] cols: g,o.  C layout: col=lane&15,row=(lane>>4)*4+r.
static __device__ __forceinline__ void act_store(
    floatx4 (&acc)[2][2], floatx4& c0, floatx4& c1,
    float bI, float bF, float bG, float bO,
    bool lo, int q, int e, int rowbase, int hcol, short* __restrict__ hout)
{
#pragma unroll
    for (int m = 0; m < 2; ++m) {
        floatx4 gi = acc[m][0];
        floatx4 gg = acc[m][1];
        float si[4], sg[4];
#pragma unroll
        for (int r = 0; r < 4; ++r) {
            si[r] = __shfl_xor(gi[r], 8);
            sg[r] = __shfl_xor(gg[r], 8);
        }
        floatx4& c = m ? c1 : c0;
#pragma unroll
        for (int r = 0; r < 4; ++r) {
            float iz = (lo ? gi[r] : si[r]) + bI;
            float fz = (lo ? si[r] : gi[r]) + bF;
            float gz = (lo ? gg[r] : sg[r]) + bG;
            float oz = (lo ? sg[r] : gg[r]) + bO;
            float ii = sigm(iz);
            float ff = sigm(fz);
            float gv = tanh_f(gz);
            float oo = sigm(oz);
            float cn = ff * c[r] + ii * gv;
            c[r] = cn;
            float hv = oo * tanh_f(cn);
            if (lo) {
                __hip_atomic_store(&hout[(size_t)(rowbase + m * 16 + q * 4 + r) * Hsz + hcol + e],
                                   f2bf(hv), __ATOMIC_RELAXED, __HIP_MEMORY_SCOPE_AGENT);
            }
        }
    }
}

__global__ __launch_bounds__(256, 1) void lstm_pers(
    const float* __restrict__ x,
    const float* __restrict__ Wih0, const float* __restrict__ Whh0,
    const float* __restrict__ bih0, const float* __restrict__ bhh0,
    const float* __restrict__ Wih1, const float* __restrict__ Whh1,
    const float* __restrict__ bih1, const float* __restrict__ bhh1,
    int* __restrict__ flags, short* __restrict__ h1ring, short* __restrict__ h2ring)
{
    __shared__ __align__(16) short w0[NGROW * W0S];   // [32][640] layer0: [Wih0 | Whh0]
    __shared__ __align__(16) short w1[NGROW * W1S];   // [32][1024] layer1: [Wih1 | Whh1]

    const int tid = threadIdx.x;
    const int bid = blockIdx.x;
    const int grp = bid >> 6;     // batch group 0..3 (64 rows each)
    const int chunk = bid & 63;   // h-chunk 0..63 (8 h elems)

    // ---- one-time: stage weight slices to LDS (bf16, XOR-swizzled within row) ----
    for (int idx = tid; idx < NGROW * 576; idx += 256) {
        int n = idx / 576;
        int k = idx - n * 576;
        int grow = (n >> 3) * Hsz + chunk * HC + (n & 7);
        float v = (k < IND) ? Wih0[grow * IND + k] : Whh0[grow * Hsz + (k - IND)];
        w0[n * W0S + (k ^ ((n & 7) << 4))] = f2bf(v);
    }
    for (int idx = tid; idx < NGROW * 1024; idx += 256) {
        int n = idx >> 10;
        int k = idx & 1023;
        int grow = (n >> 3) * Hsz + chunk * HC + (n & 7);
        float v = (k < Hsz) ? Wih1[grow * Hsz + k] : Whh1[grow * Hsz + (k - Hsz)];
        w1[n * W1S + (k ^ ((n & 7) << 4))] = f2bf(v);
    }

    const int lane = tid & 63;
    const int wv = tid >> 6;
    const int layer = wv >> 1;          // waves 0,1 -> layer0 ; waves 2,3 -> layer1
    const int wrow = (wv & 1) * 32;     // M-half
    const int q = lane >> 4;
    const int cl = lane & 15;
    const int e = lane & 7;
    const bool lo = cl < 8;
    const int rowbase = grp * 64 + wrow;
    const int hcol = chunk * HC;

    float bI, bF, bG, bO;
    {
        const float* bi = layer ? bih1 : bih0;
        const float* bh = layer ? bhh1 : bhh0;
        int hix = chunk * HC + e;
        bI = bi[hix] + bh[hix];
        bF = bi[Hsz + hix] + bh[Hsz + hix];
        bG = bi[2 * Hsz + hix] + bh[2 * Hsz + hix];
        bO = bi[3 * Hsz + hix] + bh[3 * Hsz + hix];
    }

    __syncthreads();

    floatx4 c0 = {0.f, 0.f, 0.f, 0.f};
    floatx4 c1 = {0.f, 0.f, 0.f, 0.f};
    const int fbase = grp * 512;

    for (int k = 0; k <= Tsz; ++k) {
        // ---- wait for previous iteration (h1[k-1] complete, h2[k-2] complete) ----
        if (k > 0) {
            int* fp = &flags[(fbase + k - 1) * FLAG_STRIDE];
            int spins = 0;
            while (__hip_atomic_load(fp, __ATOMIC_RELAXED, __HIP_MEMORY_SCOPE_AGENT) < 64) {
                __builtin_amdgcn_s_sleep(2);
                if (++spins > (1 << 24)) break;   // deadlock safety valve
            }
            asm volatile("" ::: "memory");   // compiler fence: no hoisting of ring loads above poll
        }

        if (layer == 0) {
            if (k < Tsz) {
                const int t = k;
                const short* h1p = h1ring + (size_t)((k + 1) & 1) * (Bsz * Hsz);  // h1[k-1] (zeros at k=0)
                floatx4 acc[2][2];
#pragma unroll
                for (int m = 0; m < 2; ++m) {
                    acc[m][0] = (floatx4){0.f, 0.f, 0.f, 0.f};
                    acc[m][1] = (floatx4){0.f, 0.f, 0.f, 0.f};
                }
#pragma unroll
                for (int ks = 0; ks < 18; ++ks) {
                    const int kk = ks * 32;
                    short8 a0, a1;
                    if (ks < 2) {
                        // x part (fp32 -> bf16)
#pragma unroll
                        for (int m = 0; m < 2; ++m) {
                            const float* xp = x + ((size_t)(rowbase + m * 16 + cl) * Tsz + t) * IND + kk + q * 8;
                            floatx4 v0 = *(const floatx4*)xp;
                            floatx4 v1 = *(const floatx4*)(xp + 4);
                            short8 av;
                            av[0] = f2bf(v0[0]); av[1] = f2bf(v0[1]); av[2] = f2bf(v0[2]); av[3] = f2bf(v0[3]);
                            av[4] = f2bf(v1[0]); av[5] = f2bf(v1[1]); av[6] = f2bf(v1[2]); av[7] = f2bf(v1[3]);
                            if (m == 0) a0 = av; else a1 = av;
                        }
                    } else {
                        a0 = ring_ld(h1p + (size_t)(rowbase + cl) * Hsz + (kk - 64) + q * 8);
                        a1 = ring_ld(h1p + (size_t)(rowbase + 16 + cl) * Hsz + (kk - 64) + q * 8);
                    }
#pragma unroll
                    for (int nt = 0; nt < 2; ++nt) {
                        const int n = nt * 16 + cl;
                        const int col = (kk + q * 8) ^ ((n & 7) << 4);
                        short8 bb = *(const short8*)(&w0[n * W0S + col]);
                        acc[0][nt] = __builtin_amdgcn_mfma_f32_16x16x32_bf16(a0, bb, acc[0][nt], 0, 0, 0);
                        acc[1][nt] = __builtin_amdgcn_mfma_f32_16x16x32_bf16(a1, bb, acc[1][nt], 0, 0, 0);
                    }
                }
                short* h1o = h1ring + (size_t)(k & 1) * (Bsz * Hsz);  // h1[k]
                act_store(acc, c0, c1, bI, bF, bG, bO, lo, q, e, rowbase, hcol, h1o);
            }
        } else {
            if (k >= 1) {
                const short* h1p = h1ring + (size_t)((k + 1) & 1) * (Bsz * Hsz);  // h1[k-1]
                const short* h2p = h2ring + (size_t)(k & 1) * (Bsz * Hsz);        // h2[k-2] (zeros at k=1)
                floatx4 acc[2][2];
#pragma unroll
                for (int m = 0; m < 2; ++m) {
                    acc[m][0] = (floatx4){0.f, 0.f, 0.f, 0.f};
                    acc[m][1] = (floatx4){0.f, 0.f, 0.f, 0.f};
                }
#pragma unroll
                for (int ks = 0; ks < 32; ++ks) {
                    const int kk = ks * 32;
                    const short* s0 = (kk < Hsz)
                        ? (h1p + (size_t)(rowbase + cl) * Hsz + kk + q * 8)
                        : (h2p + (size_t)(rowbase + cl) * Hsz + (kk - Hsz) + q * 8);
                    const short* s1 = (kk < Hsz)
                        ? (h1p + (size_t)(rowbase + 16 + cl) * Hsz + kk + q * 8)
                        : (h2p + (size_t)(rowbase + 16 + cl) * Hsz + (kk - Hsz) + q * 8);
                    short8 a0 = ring_ld(s0);
                    short8 a1 = ring_ld(s1);
#pragma unroll
                    for (int nt = 0; nt < 2; ++nt) {
                        const int n = nt * 16 + cl;
                        const int col = (kk + q * 8) ^ ((n & 7) << 4);
                        short8 bb = *(const short8*)(&w1[n * W1S + col]);
                        acc[0][nt] = __builtin_amdgcn_mfma_f32_16x16x32_bf16(a0, bb, acc[0][nt], 0, 0, 0);
                        acc[1][nt] = __builtin_amdgcn_mfma_f32_16x16x32_bf16(a1, bb, acc[1][nt], 0, 0, 0);
                    }
                }
                short* h2o = h2ring + (size_t)((k + 1) & 1) * (Bsz * Hsz);  // h2[k-1]
                act_store(acc, c0, c1, bI, bF, bG, bO, lo, q, e, rowbase, hcol, h2o);
            }
        }

        // All waves' sc1 (write-through) stores are drained by the compiler's
        // s_waitcnt vmcnt(0) before s_barrier -> relaxed flag add below is
        // ordered after all h data has reached the coherent point.
        __syncthreads();
        if (k < Tsz && tid == 0) {
            __hip_atomic_fetch_add(&flags[(fbase + k) * FLAG_STRIDE], 1,
                                   __ATOMIC_RELAXED, __HIP_MEMORY_SCOPE_AGENT);
        }
    }
}

// head: out = sigmoid(relu(h2_last @ W1^T + b1) @ W2^T + b2)
__global__ void __launch_bounds__(256) head_kernel(
    const short* __restrict__ h2,   // final h2 (slot 1), [256][512] bf16
    const float* __restrict__ W1, const float* __restrict__ b1,
    const float* __restrict__ W2, const float* __restrict__ b2,
    float* __restrict__ out)
{
    __shared__ float hid[4][256];
    const int tid = threadIdx.x;
    const int r0 = blockIdx.x * 4;
    float acc[4] = {0.f, 0.f, 0.f, 0.f};
    const float* wrow = W1 + (size_t)tid * 512;
    for (int kk = 0; kk < 512; kk += 8) {
        float w[8];
#pragma unroll
        for (int j = 0; j < 8; ++j) w[j] = wrow[kk + j];
#pragma unroll
        for (int r = 0; r < 4; ++r) {
            short8 hv = *(const short8*)(h2 + (size_t)(r0 + r) * 512 + kk);
#pragma unroll
            for (int j = 0; j < 8; ++j) acc[r] += w[j] * bf2f(hv[j]);
        }
    }
#pragma unroll
    for (int r = 0; r < 4; ++r) hid[r][tid] = fmaxf(acc[r] + b1[tid], 0.f);
    __syncthreads();
    const int wv = tid >> 6, lane = tid & 63;
    float s = 0.f;
    for (int j = lane; j < 256; j += 64) s += hid[wv][j] * W2[j];
#pragma unroll
    for (int off = 32; off; off >>= 1) s += __shfl_down(s, off, 64);
    if (lane == 0) out[r0 + wv] = 1.f / (1.f + __expf(-(s + b2[0])));
}

extern "C" void kernel_launch(void* const* d_in, const int* in_sizes, int n_in,
                              void* d_out, int out_size, void* d_ws, size_t ws_size,
                              hipStream_t stream) {
    const float* x    = (const float*)d_in[0];
    const float* Wih0 = (const float*)d_in[1];
    const float* Whh0 = (const float*)d_in[2];
    const float* bih0 = (const float*)d_in[3];
    const float* bhh0 = (const float*)d_in[4];
    const float* Wih1 = (const float*)d_in[5];
    const float* Whh1 = (const float*)d_in[6];
    const float* bih1 = (const float*)d_in[7];
    const float* bhh1 = (const float*)d_in[8];
    const float* W1   = (const float*)d_in[9];
    const float* b1   = (const float*)d_in[10];
    const float* W2   = (const float*)d_in[11];
    const float* b2   = (const float*)d_in[12];
    float* out = (float*)d_out;

    const size_t FLAGS_BYTES = (size_t)4 * 512 * FLAG_STRIDE * sizeof(int);  // 128 KB
    const size_t RING_BYTES  = (size_t)2 * Bsz * Hsz * sizeof(short);        // 512 KB
    if (ws_size < FLAGS_BYTES + 2 * RING_BYTES) return;

    char* ws = (char*)d_ws;
    int*   flags  = (int*)ws;
    short* h1ring = (short*)(ws + FLAGS_BYTES);
    short* h2ring = (short*)(ws + FLAGS_BYTES + RING_BYTES);

    // zero flags + rings (rings double as the h[-1]=0 initial state)
    hipMemsetAsync(d_ws, 0, FLAGS_BYTES + 2 * RING_BYTES, stream);

    void* args[] = {
        (void*)&x,
        (void*)&Wih0, (void*)&Whh0, (void*)&bih0, (void*)&bhh0,
        (void*)&Wih1, (void*)&Whh1, (void*)&bih1, (void*)&bhh1,
        (void*)&flags, (void*)&h1ring, (void*)&h2ring
    };
    hipLaunchCooperativeKernel((const void*)lstm_pers, dim3(256), dim3(256), args, 0, stream);

    const short* h2last = h2ring + (size_t)Bsz * Hsz;  // slot 1 holds h2[T-1]
    head_kernel<<<dim3(64), dim3(256), 0, stream>>>(h2last, W1, b1, W2, b2, out);
}

// Round 4
// 4856.351 us; speedup vs baseline: 2.3944x; 1.7865x over previous
//
#include <hip/hip_runtime.h>
#include <hip/hip_bf16.h>
#include <stdint.h>

// SeqLSTM: 2-layer LSTM (B=256,T=512,IN=64,H=512) + MLP head.
// Persistent LAYER-SPECIALIZED kernel: 256 WGs = 4 batch groups x (32 L0-chunks + 32 L1-chunks).
// Each WG: 512 threads = 8 waves = 4 M-slots x 2 K-halves (split-K, LDS f32 partial buffer).
// Weights LDS-resident (bf16, XOR-swizzled). h exchanged via global bf16 rings with
// 16B inline-asm sc1 loads (agent-coherent, bypass stale L2), two-phase issue:
// all loads -> s_waitcnt vmcnt(0) -> sched_barrier -> MFMA block.
// Cross-WG sync: per-(group,iter) relaxed flag counters (64 WGs each), wave-0-only poll.

#define Bsz 256
#define Tsz 512
#define IND 64
#define Hsz 512
#define BH (Bsz * Hsz)
#define FLAG_STRIDE 16   // ints -> 64B per flag line

typedef __attribute__((ext_vector_type(8))) short short8;
typedef __attribute__((ext_vector_type(4))) float floatx4;

static __device__ __forceinline__ short f2bf(float f) {
    unsigned u = __float_as_uint(f);
    u += 0x7FFFu + ((u >> 16) & 1u);   // RNE
    return (short)(u >> 16);
}
static __device__ __forceinline__ float bf2f(short s) {
    return __uint_as_float(((unsigned)(unsigned short)s) << 16);
}
static __device__ __forceinline__ float sigm(float z) { return 1.f / (1.f + __expf(-z)); }
static __device__ __forceinline__ float tanh_f(float z) { return 2.f / (1.f + __expf(-2.f * z)) - 1.f; }

// 16B agent-coherent ring load (sc1: read at the coherence point / MALL, skip stale L2).
// NOTE: asm result is NOT vmcnt-tracked by the compiler -> callers MUST execute
// s_waitcnt vmcnt(0) + sched_barrier(0) before consuming (done in the two-phase blocks).
static __device__ __forceinline__ short8 ring16(const short* p) {
    short8 v;
    asm volatile("global_load_dwordx4 %0, %1, off sc1" : "=v"(v) : "v"(p));
    return v;
}

__global__ __launch_bounds__(512, 1) void lstm_pers(
    const float* __restrict__ x,
    const float* __restrict__ Wih0, const float* __restrict__ Whh0,
    const float* __restrict__ bih0, const float* __restrict__ bhh0,
    const float* __restrict__ Wih1, const float* __restrict__ Whh1,
    const float* __restrict__ bih1, const float* __restrict__ bhh1,
    int* __restrict__ flags, short* __restrict__ h1ring, short* __restrict__ h2ring)
{
    // L0 WG: w = [64][640] bf16 (Wih0|Whh0, pad for XOR swizzle) = 80KB
    // L1 WG: w = [64][1024] bf16 (Wih1|Whh1) = 128KB
    // p1 = [64][65] f32 split-K partial buffer = 16.25KB  (total 147712B <= 160KB)
    __shared__ __align__(16) char smem[147712];
    short* w  = (short*)smem;
    float* p1 = (float*)(smem + 131072);

    const int tid = threadIdx.x;
    const int bid = blockIdx.x;
    const int layer = bid >> 7;      // 0..127 -> layer0, 128..255 -> layer1
    const int lb    = bid & 127;
    const int grp   = lb >> 5;       // batch group 0..3 (64 rows)
    const int chunk = lb & 31;       // 16 h-elems per chunk

    // ---- one-time: stage weight slices to LDS (bf16, XOR-swizzled within row) ----
    if (layer == 0) {
        for (int idx = tid; idx < 64 * 576; idx += 512) {
            int n = idx / 576, kc = idx - n * 576;
            int grow = (n >> 4) * Hsz + chunk * 16 + (n & 15);
            float v = (kc < IND) ? Wih0[grow * IND + kc]
                                 : Whh0[(size_t)grow * Hsz + kc - IND];
            w[n * 640 + (kc ^ ((n & 7) << 4))] = f2bf(v);
        }
    } else {
        for (int idx = tid; idx < 64 * 1024; idx += 512) {
            int n = idx >> 10, kc = idx & 1023;
            int grow = (n >> 4) * Hsz + chunk * 16 + (n & 15);
            float v = (kc < Hsz) ? Wih1[(size_t)grow * Hsz + kc]
                                 : Whh1[(size_t)grow * Hsz + kc - Hsz];
            w[n * 1024 + (kc ^ ((n & 7) << 4))] = f2bf(v);
        }
    }

    const int lane  = tid & 63;
    const int wv    = tid >> 6;      // 0..7
    const int mslot = wv >> 1;       // 4 M-slots x 16 rows
    const int kh    = wv & 1;        // split-K half
    const int q     = lane >> 4;     // 0..3
    const int cl    = lane & 15;     // MFMA row/col-in-fragment
    const int rowbase = grp * 64 + mslot * 16;
    const int hcol    = chunk * 16;

    float bI, bF, bG, bO;
    {
        const float* bi = layer ? bih1 : bih0;
        const float* bh = layer ? bhh1 : bhh0;
        int hix = hcol + cl;
        bI = bi[hix] + bh[hix];
        bF = bi[Hsz + hix] + bh[Hsz + hix];
        bG = bi[2 * Hsz + hix] + bh[2 * Hsz + hix];
        bO = bi[3 * Hsz + hix] + bh[3 * Hsz + hix];
    }

    __syncthreads();

    floatx4 c = {0.f, 0.f, 0.f, 0.f};   // cell state (kh==0 waves only use it)
    const int fbase = grp * 512;

    for (int k = 0; k <= Tsz; ++k) {
        // ---- wave 0 polls iteration k-1 completion; others wait at barrier A ----
        if (k > 0 && wv == 0) {
            int* fp = &flags[(fbase + k - 1) * FLAG_STRIDE];
            int spins = 0;
            while (__hip_atomic_load(fp, __ATOMIC_RELAXED, __HIP_MEMORY_SCOPE_AGENT) < 64) {
                __builtin_amdgcn_s_sleep(1);
                if (++spins > (1 << 24)) break;   // deadlock safety valve
            }
        }
        __syncthreads();                          // A
        asm volatile("" ::: "memory");

        const bool active = layer ? (k >= 1) : (k < Tsz);
        floatx4 acc[4];
#pragma unroll
        for (int nt = 0; nt < 4; ++nt) acc[nt] = (floatx4){0.f, 0.f, 0.f, 0.f};

        if (active) {
            if (layer == 0) {
                // K = 576 = x(64) | h1[k-1](512); kh0: ks 0..8, kh1: ks 9..17
                const short* h1p = h1ring + (size_t)((k + 1) & 1) * BH;
                const short* abase = h1p + (size_t)(rowbase + cl) * Hsz + q * 8;
                short8 af[9];
                if (kh == 0) {
#pragma unroll
                    for (int i = 2; i < 9; ++i) af[i] = ring16(abase + i * 32 - 64);
#pragma unroll
                    for (int i = 0; i < 2; ++i) {
                        const float* xp = x + ((size_t)(rowbase + cl) * Tsz + k) * IND + i * 32 + q * 8;
                        floatx4 v0 = *(const floatx4*)xp;
                        floatx4 v1 = *(const floatx4*)(xp + 4);
                        short8 av;
                        av[0] = f2bf(v0[0]); av[1] = f2bf(v0[1]); av[2] = f2bf(v0[2]); av[3] = f2bf(v0[3]);
                        av[4] = f2bf(v1[0]); av[5] = f2bf(v1[1]); av[6] = f2bf(v1[2]); av[7] = f2bf(v1[3]);
                        af[i] = av;
                    }
                } else {
#pragma unroll
                    for (int i = 0; i < 9; ++i) af[i] = ring16(abase + (9 + i) * 32 - 64);
                }
                asm volatile("s_waitcnt vmcnt(0)" ::: "memory");
                __builtin_amdgcn_sched_barrier(0);
#pragma unroll
                for (int i = 0; i < 9; ++i) {
                    const int kk = (kh * 9 + i) * 32;
#pragma unroll
                    for (int nt = 0; nt < 4; ++nt) {
                        const int n = nt * 16 + cl;
                        const int col = (kk + q * 8) ^ ((n & 7) << 4);
                        short8 bb = *(const short8*)&w[n * 640 + col];
                        acc[nt] = __builtin_amdgcn_mfma_f32_16x16x32_bf16(af[i], bb, acc[nt], 0, 0, 0);
                    }
                }
            } else {
                // K = 1024 = h1[k-1](512) | h2[k-2](512); kh0 streams h1, kh1 streams h2
                const short* h1p = h1ring + (size_t)((k + 1) & 1) * BH;
                const short* h2p = h2ring + (size_t)(k & 1) * BH;
                const short* src = (kh ? h2p : h1p) + (size_t)(rowbase + cl) * Hsz + q * 8;
                short8 af[16];
#pragma unroll
                for (int i = 0; i < 16; ++i) af[i] = ring16(src + i * 32);
                asm volatile("s_waitcnt vmcnt(0)" ::: "memory");
                __builtin_amdgcn_sched_barrier(0);
#pragma unroll
                for (int i = 0; i < 16; ++i) {
                    const int kk = (kh * 16 + i) * 32;
#pragma unroll
                    for (int nt = 0; nt < 4; ++nt) {
                        const int n = nt * 16 + cl;
                        const int col = (kk + q * 8) ^ ((n & 7) << 4);
                        short8 bb = *(const short8*)&w[n * 1024 + col];
                        acc[nt] = __builtin_amdgcn_mfma_f32_16x16x32_bf16(af[i], bb, acc[nt], 0, 0, 0);
                    }
                }
            }
            if (kh) {   // publish K-half-1 partial sums
#pragma unroll
                for (int nt = 0; nt < 4; ++nt)
#pragma unroll
                    for (int r = 0; r < 4; ++r)
                        p1[(mslot * 16 + q * 4 + r) * 65 + nt * 16 + cl] = acc[nt][r];
            }
        }

        __syncthreads();                          // B (p1 visible)

        if (active && kh == 0) {
            short* hout = layer ? (h2ring + (size_t)((k + 1) & 1) * BH)
                                : (h1ring + (size_t)(k & 1) * BH);
            // gate nt: 0=i 1=f 2=g 3=o, all in-thread (no shuffles); C row = q*4+r, col(e)=cl
#pragma unroll
            for (int r = 0; r < 4; ++r) {
                const int prow = (mslot * 16 + q * 4 + r) * 65;
                float iz = acc[0][r] + p1[prow + cl]      + bI;
                float fz = acc[1][r] + p1[prow + 16 + cl] + bF;
                float gz = acc[2][r] + p1[prow + 32 + cl] + bG;
                float oz = acc[3][r] + p1[prow + 48 + cl] + bO;
                float ii = sigm(iz);
                float ff = sigm(fz);
                float gg = tanh_f(gz);
                float oo = sigm(oz);
                float cn = ff * c[r] + ii * gg;
                c[r] = cn;
                float hv = oo * tanh_f(cn);
                __hip_atomic_store(&hout[(size_t)(rowbase + q * 4 + r) * Hsz + hcol + cl],
                                   f2bf(hv), __ATOMIC_RELAXED, __HIP_MEMORY_SCOPE_AGENT);
            }
        }

        // Barrier C: drains all waves' sc1 h-stores (vmcnt(0) before s_barrier),
        // so the relaxed flag add below is ordered after the data.
        __syncthreads();                          // C
        if (k < Tsz && tid == 0) {
            __hip_atomic_fetch_add(&flags[(fbase + k) * FLAG_STRIDE], 1,
                                   __ATOMIC_RELAXED, __HIP_MEMORY_SCOPE_AGENT);
        }
    }
}

// head: out = sigmoid(relu(h2_last @ W1^T + b1) @ W2^T + b2)
__global__ void __launch_bounds__(256) head_kernel(
    const short* __restrict__ h2,   // final h2 (slot 1), [256][512] bf16
    const float* __restrict__ W1, const float* __restrict__ b1,
    const float* __restrict__ W2, const float* __restrict__ b2,
    float* __restrict__ out)
{
    __shared__ float hid[4][256];
    const int tid = threadIdx.x;
    const int r0 = blockIdx.x * 4;
    float acc[4] = {0.f, 0.f, 0.f, 0.f};
    const float* wrow = W1 + (size_t)tid * 512;
    for (int kk = 0; kk < 512; kk += 8) {
        float wv8[8];
#pragma unroll
        for (int j = 0; j < 8; ++j) wv8[j] = wrow[kk + j];
#pragma unroll
        for (int r = 0; r < 4; ++r) {
            short8 hv = *(const short8*)(h2 + (size_t)(r0 + r) * 512 + kk);
#pragma unroll
            for (int j = 0; j < 8; ++j) acc[r] += wv8[j] * bf2f(hv[j]);
        }
    }
#pragma unroll
    for (int r = 0; r < 4; ++r) hid[r][tid] = fmaxf(acc[r] + b1[tid], 0.f);
    __syncthreads();
    const int wv = tid >> 6, lane = tid & 63;
    float s = 0.f;
    for (int j = lane; j < 256; j += 64) s += hid[wv][j] * W2[j];
#pragma unroll
    for (int off = 32; off; off >>= 1) s += __shfl_down(s, off, 64);
    if (lane == 0) out[r0 + wv] = 1.f / (1.f + __expf(-(s + b2[0])));
}

extern "C" void kernel_launch(void* const* d_in, const int* in_sizes, int n_in,
                              void* d_out, int out_size, void* d_ws, size_t ws_size,
                              hipStream_t stream) {
    const float* x    = (const float*)d_in[0];
    const float* Wih0 = (const float*)d_in[1];
    const float* Whh0 = (const float*)d_in[2];
    const float* bih0 = (const float*)d_in[3];
    const float* bhh0 = (const float*)d_in[4];
    const float* Wih1 = (const float*)d_in[5];
    const float* Whh1 = (const float*)d_in[6];
    const float* bih1 = (const float*)d_in[7];
    const float* bhh1 = (const float*)d_in[8];
    const float* W1   = (const float*)d_in[9];
    const float* b1   = (const float*)d_in[10];
    const float* W2   = (const float*)d_in[11];
    const float* b2   = (const float*)d_in[12];
    float* out = (float*)d_out;

    const size_t FLAGS_BYTES = (size_t)4 * 512 * FLAG_STRIDE * sizeof(int);  // 128 KB
    const size_t RING_BYTES  = (size_t)2 * Bsz * Hsz * sizeof(short);        // 512 KB
    if (ws_size < FLAGS_BYTES + 2 * RING_BYTES) return;

    char* ws = (char*)d_ws;
    int*   flags  = (int*)ws;
    short* h1ring = (short*)(ws + FLAGS_BYTES);
    short* h2ring = (short*)(ws + FLAGS_BYTES + RING_BYTES);

    // zero flags + rings (rings double as the h[-1]=0 initial state)
    hipMemsetAsync(d_ws, 0, FLAGS_BYTES + 2 * RING_BYTES, stream);

    void* args[] = {
        (void*)&x,
        (void*)&Wih0, (void*)&Whh0, (void*)&bih0, (void*)&bhh0,
        (void*)&Wih1, (void*)&Whh1, (void*)&bih1, (void*)&bhh1,
        (void*)&flags, (void*)&h1ring, (void*)&h2ring
    };
    hipLaunchCooperativeKernel((const void*)lstm_pers, dim3(256), dim3(512), args, 0, stream);

    const short* h2last = h2ring + (size_t)Bsz * Hsz;  // slot 1 holds h2[T-1]
    head_kernel<<<dim3(64), dim3(256), 0, stream>>>(h2last, W1, b1, W2, b2, out);
}

// Round 5
// 4806.914 us; speedup vs baseline: 2.4190x; 1.0103x over previous
//
#include <hip/hip_runtime.h>
#include <hip/hip_bf16.h>
#include <stdint.h>

// SeqLSTM: 2-layer LSTM (B=256,T=512,IN=64,H=512) + MLP head.
// Persistent LAYER-SPECIALIZED kernel: 256 WGs = 4 batch groups x (32 L0-chunks + 32 L1-chunks).
// Each WG: 512 threads = 8 waves = 4 M-slots x 2 K-halves (split-K, LDS f32 partial buffer).
// Weights LDS-resident (bf16, XOR-swizzled). h exchanged via global bf16 rings with
// 16B inline-asm sc1 loads (agent-coherent), two-phase issue: loads -> vmcnt(0) -> MFMA.
// Cross-WG sync: PER-WG EPOCH SLOTS (relaxed sc1 stores, no RMW serialization);
// every wave polls its group's 64 slots with one 64-lane load (no barrier relay).

#define Bsz 256
#define Tsz 512
#define IND 64
#define Hsz 512
#define BH (Bsz * Hsz)
#define P1S 66           // p1 row stride (f32): 4*66 mod 32 = 8 -> 2-way banks (free)

typedef __attribute__((ext_vector_type(8))) short short8;
typedef __attribute__((ext_vector_type(4))) float floatx4;

static __device__ __forceinline__ short f2bf(float f) {
    unsigned u = __float_as_uint(f);
    u += 0x7FFFu + ((u >> 16) & 1u);   // RNE
    return (short)(u >> 16);
}
static __device__ __forceinline__ float bf2f(short s) {
    return __uint_as_float(((unsigned)(unsigned short)s) << 16);
}
static __device__ __forceinline__ float sigm(float z) { return 1.f / (1.f + __expf(-z)); }
static __device__ __forceinline__ float tanh_f(float z) { return 2.f / (1.f + __expf(-2.f * z)) - 1.f; }

// 16B agent-coherent ring load (sc1: served at the coherence point, skips stale L2).
// Result is NOT vmcnt-tracked by the compiler -> two-phase blocks below execute
// s_waitcnt vmcnt(0) + sched_barrier(0) before consuming.
static __device__ __forceinline__ short8 ring16(const short* p) {
    short8 v;
    asm volatile("global_load_dwordx4 %0, %1, off sc1" : "=v"(v) : "v"(p));
    return v;
}

__global__ __launch_bounds__(512, 1) void lstm_pers(
    const float* __restrict__ x,
    const float* __restrict__ Wih0, const float* __restrict__ Whh0,
    const float* __restrict__ bih0, const float* __restrict__ bhh0,
    const float* __restrict__ Wih1, const float* __restrict__ Whh1,
    const float* __restrict__ bih1, const float* __restrict__ bhh1,
    int* __restrict__ slots, short* __restrict__ h1ring, short* __restrict__ h2ring)
{
    // L0 WG: w = [64][640] bf16 (Wih0|Whh0, XOR-swizzle pad) = 80KB
    // L1 WG: w = [64][1024] bf16 (Wih1|Whh1) = 128KB
    // p1 = [64][66] f32 split-K partial buffer = 16.5KB  (total 147968B <= 160KB)
    __shared__ __align__(16) char smem[131072 + 64 * P1S * 4];
    short* w  = (short*)smem;
    float* p1 = (float*)(smem + 131072);

    const int tid = threadIdx.x;
    const int bid = blockIdx.x;
    const int layer = bid >> 7;      // 0..127 -> layer0, 128..255 -> layer1
    const int lb    = bid & 127;
    const int grp   = lb >> 5;       // batch group 0..3 (64 rows)
    const int chunk = lb & 31;       // 16 h-elems per chunk
    const int sid   = layer * 32 + chunk;   // my epoch slot within the group

    // ---- one-time: stage weight slices to LDS (bf16, XOR-swizzled within row) ----
    if (layer == 0) {
        for (int idx = tid; idx < 64 * 576; idx += 512) {
            int n = idx / 576, kc = idx - n * 576;
            int grow = (n >> 4) * Hsz + chunk * 16 + (n & 15);
            float v = (kc < IND) ? Wih0[grow * IND + kc]
                                 : Whh0[(size_t)grow * Hsz + kc - IND];
            w[n * 640 + (kc ^ ((n & 7) << 4))] = f2bf(v);
        }
    } else {
        for (int idx = tid; idx < 64 * 1024; idx += 512) {
            int n = idx >> 10, kc = idx & 1023;
            int grow = (n >> 4) * Hsz + chunk * 16 + (n & 15);
            float v = (kc < Hsz) ? Wih1[(size_t)grow * Hsz + kc]
                                 : Whh1[(size_t)grow * Hsz + kc - Hsz];
            w[n * 1024 + (kc ^ ((n & 7) << 4))] = f2bf(v);
        }
    }

    const int lane  = tid & 63;
    const int wv    = tid >> 6;      // 0..7
    const int mslot = wv >> 1;       // 4 M-slots x 16 rows
    const int kh    = wv & 1;        // split-K half
    const int q     = lane >> 4;     // 0..3
    const int cl    = lane & 15;     // MFMA row/col-in-fragment
    const int rowbase = grp * 64 + mslot * 16;
    const int hcol    = chunk * 16;

    float bI, bF, bG, bO;
    {
        const float* bi = layer ? bih1 : bih0;
        const float* bh = layer ? bhh1 : bhh0;
        int hix = hcol + cl;
        bI = bi[hix] + bh[hix];
        bF = bi[Hsz + hix] + bh[Hsz + hix];
        bG = bi[2 * Hsz + hix] + bh[2 * Hsz + hix];
        bO = bi[3 * Hsz + hix] + bh[3 * Hsz + hix];
    }

    __syncthreads();

    floatx4 c = {0.f, 0.f, 0.f, 0.f};   // cell state (kh==0 waves only)
    const int* myslots = &slots[grp * 64 + lane];

    for (int k = 0; k <= Tsz; ++k) {
        const bool active = layer ? (k >= 1) : (k < Tsz);
        short8 af[16];

        // ---- x prefetch+convert (flag-independent) for L0/kh0 ----
        if (active && layer == 0 && kh == 0) {
#pragma unroll
            for (int i = 0; i < 2; ++i) {
                const float* xp = x + ((size_t)(rowbase + cl) * Tsz + k) * IND + i * 32 + q * 8;
                floatx4 v0 = *(const floatx4*)xp;
                floatx4 v1 = *(const floatx4*)(xp + 4);
                short8 av;
                av[0] = f2bf(v0[0]); av[1] = f2bf(v0[1]); av[2] = f2bf(v0[2]); av[3] = f2bf(v0[3]);
                av[4] = f2bf(v1[0]); av[5] = f2bf(v1[1]); av[6] = f2bf(v1[2]); av[7] = f2bf(v1[3]);
                af[i] = av;
            }
        }

        // ---- every wave polls: all 64 group slots >= k (lane i watches slot i) ----
        if (k > 0) {
            int v = __hip_atomic_load(myslots, __ATOMIC_RELAXED, __HIP_MEMORY_SCOPE_AGENT);
            int spins = 0;
            while (v < k) {
                __builtin_amdgcn_s_sleep(1);
                v = __hip_atomic_load(myslots, __ATOMIC_RELAXED, __HIP_MEMORY_SCOPE_AGENT);
                if (++spins > (1 << 22)) break;   // deadlock safety valve
            }
            asm volatile("" ::: "memory");   // no hoisting of ring loads above poll
        }

        floatx4 acc[4];
#pragma unroll
        for (int nt = 0; nt < 4; ++nt) acc[nt] = (floatx4){0.f, 0.f, 0.f, 0.f};

        if (active) {
            if (layer == 0) {
                // K = 576 = x(64) | h1[k-1](512); kh0: ks 0..8, kh1: ks 9..17
                const short* h1p = h1ring + (size_t)((k + 1) & 1) * BH;
                const short* abase = h1p + (size_t)(rowbase + cl) * Hsz + q * 8;
                if (kh == 0) {
#pragma unroll
                    for (int i = 2; i < 9; ++i) af[i] = ring16(abase + i * 32 - 64);
                } else {
#pragma unroll
                    for (int i = 0; i < 9; ++i) af[i] = ring16(abase + (9 + i) * 32 - 64);
                }
                asm volatile("s_waitcnt vmcnt(0)" ::: "memory");
                __builtin_amdgcn_sched_barrier(0);
#pragma unroll
                for (int i = 0; i < 9; ++i) {
                    const int kk = (kh * 9 + i) * 32;
#pragma unroll
                    for (int nt = 0; nt < 4; ++nt) {
                        const int n = nt * 16 + cl;
                        const int col = (kk + q * 8) ^ ((n & 7) << 4);
                        short8 bb = *(const short8*)&w[n * 640 + col];
                        acc[nt] = __builtin_amdgcn_mfma_f32_16x16x32_bf16(af[i], bb, acc[nt], 0, 0, 0);
                    }
                }
            } else {
                // K = 1024 = h1[k-1](512) | h2[k-2](512); kh0 streams h1, kh1 streams h2
                const short* h1p = h1ring + (size_t)((k + 1) & 1) * BH;
                const short* h2p = h2ring + (size_t)(k & 1) * BH;
                const short* src = (kh ? h2p : h1p) + (size_t)(rowbase + cl) * Hsz + q * 8;
#pragma unroll
                for (int i = 0; i < 16; ++i) af[i] = ring16(src + i * 32);
                asm volatile("s_waitcnt vmcnt(0)" ::: "memory");
                __builtin_amdgcn_sched_barrier(0);
#pragma unroll
                for (int i = 0; i < 16; ++i) {
                    const int kk = (kh * 16 + i) * 32;
#pragma unroll
                    for (int nt = 0; nt < 4; ++nt) {
                        const int n = nt * 16 + cl;
                        const int col = (kk + q * 8) ^ ((n & 7) << 4);
                        short8 bb = *(const short8*)&w[n * 1024 + col];
                        acc[nt] = __builtin_amdgcn_mfma_f32_16x16x32_bf16(af[i], bb, acc[nt], 0, 0, 0);
                    }
                }
            }
            if (kh) {   // publish K-half-1 partial sums
#pragma unroll
                for (int nt = 0; nt < 4; ++nt)
#pragma unroll
                    for (int r = 0; r < 4; ++r)
                        p1[(mslot * 16 + q * 4 + r) * P1S + nt * 16 + cl] = acc[nt][r];
            }
        }

        __syncthreads();                          // B (p1 visible)

        if (active && kh == 0) {
            short* hout = layer ? (h2ring + (size_t)((k + 1) & 1) * BH)
                                : (h1ring + (size_t)(k & 1) * BH);
            // gate nt: 0=i 1=f 2=g 3=o, all in-thread; C row = q*4+r, col(e)=cl
#pragma unroll
            for (int r = 0; r < 4; ++r) {
                const int prow = (mslot * 16 + q * 4 + r) * P1S;
                float iz = acc[0][r] + p1[prow + cl]      + bI;
                float fz = acc[1][r] + p1[prow + 16 + cl] + bF;
                float gz = acc[2][r] + p1[prow + 32 + cl] + bG;
                float oz = acc[3][r] + p1[prow + 48 + cl] + bO;
                float ii = sigm(iz);
                float ff = sigm(fz);
                float gg = tanh_f(gz);
                float oo = sigm(oz);
                float cn = ff * c[r] + ii * gg;
                c[r] = cn;
                float hv = oo * tanh_f(cn);
                __hip_atomic_store(&hout[(size_t)(rowbase + q * 4 + r) * Hsz + hcol + cl],
                                   f2bf(hv), __ATOMIC_RELAXED, __HIP_MEMORY_SCOPE_AGENT);
            }
        }

        // Barrier C: every wave drains its own vmcnt before s_barrier, so all h
        // stores are at the coherence point before tid 0 posts the epoch.
        __syncthreads();                          // C
        if (k < Tsz && tid == 0) {
            __hip_atomic_store(&slots[grp * 64 + sid], k + 1,
                               __ATOMIC_RELAXED, __HIP_MEMORY_SCOPE_AGENT);
        }
    }
}

// head: out = sigmoid(relu(h2_last @ W1^T + b1) @ W2^T + b2)
__global__ void __launch_bounds__(256) head_kernel(
    const short* __restrict__ h2,   // final h2 (slot 1), [256][512] bf16
    const float* __restrict__ W1, const float* __restrict__ b1,
    const float* __restrict__ W2, const float* __restrict__ b2,
    float* __restrict__ out)
{
    __shared__ float hid[4][256];
    const int tid = threadIdx.x;
    const int r0 = blockIdx.x * 4;
    float acc[4] = {0.f, 0.f, 0.f, 0.f};
    const float* wrow = W1 + (size_t)tid * 512;
    for (int kk = 0; kk < 512; kk += 8) {
        float wv8[8];
#pragma unroll
        for (int j = 0; j < 8; ++j) wv8[j] = wrow[kk + j];
#pragma unroll
        for (int r = 0; r < 4; ++r) {
            short8 hv = *(const short8*)(h2 + (size_t)(r0 + r) * 512 + kk);
#pragma unroll
            for (int j = 0; j < 8; ++j) acc[r] += wv8[j] * bf2f(hv[j]);
        }
    }
#pragma unroll
    for (int r = 0; r < 4; ++r) hid[r][tid] = fmaxf(acc[r] + b1[tid], 0.f);
    __syncthreads();
    const int wv = tid >> 6, lane = tid & 63;
    float s = 0.f;
    for (int j = lane; j < 256; j += 64) s += hid[wv][j] * W2[j];
#pragma unroll
    for (int off = 32; off; off >>= 1) s += __shfl_down(s, off, 64);
    if (lane == 0) out[r0 + wv] = 1.f / (1.f + __expf(-(s + b2[0])));
}

extern "C" void kernel_launch(void* const* d_in, const int* in_sizes, int n_in,
                              void* d_out, int out_size, void* d_ws, size_t ws_size,
                              hipStream_t stream) {
    const float* x    = (const float*)d_in[0];
    const float* Wih0 = (const float*)d_in[1];
    const float* Whh0 = (const float*)d_in[2];
    const float* bih0 = (const float*)d_in[3];
    const float* bhh0 = (const float*)d_in[4];
    const float* Wih1 = (const float*)d_in[5];
    const float* Whh1 = (const float*)d_in[6];
    const float* bih1 = (const float*)d_in[7];
    const float* bhh1 = (const float*)d_in[8];
    const float* W1   = (const float*)d_in[9];
    const float* b1   = (const float*)d_in[10];
    const float* W2   = (const float*)d_in[11];
    const float* b2   = (const float*)d_in[12];
    float* out = (float*)d_out;

    const size_t SLOTS_BYTES = (size_t)4 * 64 * sizeof(int);          // 1 KB epoch slots
    const size_t RING_BYTES  = (size_t)2 * Bsz * Hsz * sizeof(short); // 512 KB
    if (ws_size < SLOTS_BYTES + 2 * RING_BYTES) return;

    char* ws = (char*)d_ws;
    int*   slots  = (int*)ws;
    short* h1ring = (short*)(ws + SLOTS_BYTES);
    short* h2ring = (short*)(ws + SLOTS_BYTES + RING_BYTES);

    // zero slots + rings (rings double as the h[-1]=0 initial state)
    hipMemsetAsync(d_ws, 0, SLOTS_BYTES + 2 * RING_BYTES, stream);

    void* args[] = {
        (void*)&x,
        (void*)&Wih0, (void*)&Whh0, (void*)&bih0, (void*)&bhh0,
        (void*)&Wih1, (void*)&Whh1, (void*)&bih1, (void*)&bhh1,
        (void*)&slots, (void*)&h1ring, (void*)&h2ring
    };
    hipLaunchCooperativeKernel((const void*)lstm_pers, dim3(256), dim3(512), args, 0, stream);

    const short* h2last = h2ring + (size_t)Bsz * Hsz;  // slot 1 holds h2[T-1]
    head_kernel<<<dim3(64), dim3(256), 0, stream>>>(h2last, W1, b1, W2, b2, out);
}